// Round 11
// baseline (273.401 us; speedup 1.0000x reference)
//
#include <hip/hip_runtime.h>
#include <stdint.h>

#define BB 2
#define LL 2048
#define DD 1024
#define NHH 16
#define HSS 64

typedef __bf16 bf16x8 __attribute__((ext_vector_type(8)));
typedef float f32x4 __attribute__((ext_vector_type(4)));

// Load 8 consecutive elements as bf16x8, converting from fp32 if needed.
__device__ __forceinline__ bf16x8 load8(const float* p) {
  float4 f0 = *(const float4*)p;
  float4 f1 = *(const float4*)(p + 4);
  bf16x8 v;
  v[0] = (__bf16)f0.x; v[1] = (__bf16)f0.y; v[2] = (__bf16)f0.z; v[3] = (__bf16)f0.w;
  v[4] = (__bf16)f1.x; v[5] = (__bf16)f1.y; v[6] = (__bf16)f1.z; v[7] = (__bf16)f1.w;
  return v;
}
__device__ __forceinline__ bf16x8 load8(const __bf16* p) {
  return *(const bf16x8*)p;
}

// Async global->LDS DMA, 16B/lane. LDS dest WAVE-UNIFORM base; HW writes
// lane l at base + l*16 (m97-verified). Target LDS must be unpadded.
__device__ __forceinline__ void async_ld16(__bf16* lds_uniform_base,
                                           const __bf16* gptr_per_lane) {
  __builtin_amdgcn_global_load_lds(
      (const __attribute__((address_space(1))) void*)gptr_per_lane,
      (__attribute__((address_space(3))) void*)lds_uniform_base, 16, 0, 0);
}

// ---------------------------------------------------------------- prep (fused)
// z=0: Wqkv fp32 [1024][3072] -> WqkvT bf16 [3072][1024]   (3072 tiles)
// z=1: x fp32 -> xb bf16 elementwise (4.19M elems)          (2048 blocks)
// z=2: Er fp32 -> Erb bf16 elementwise (131072 elems)       (64 blocks)
__global__ void prep_k(const float* __restrict__ Wqkv, const float* __restrict__ x,
                       const float* __restrict__ Er, __bf16* __restrict__ WqkvT,
                       __bf16* __restrict__ xb, __bf16* __restrict__ Erb) {
  int tx = threadIdx.x, ty = threadIdx.y;
  int tid = ty * 32 + tx;
  if (blockIdx.z == 1) {
    if (blockIdx.x >= 2048) return;
    size_t off = ((size_t)blockIdx.x * 256 + tid) * 8;
    *(bf16x8*)&xb[off] = load8(&x[off]);
    return;
  }
  if (blockIdx.z == 2) {
    if (blockIdx.x >= 64) return;
    size_t off = ((size_t)blockIdx.x * 256 + tid) * 8;
    *(bf16x8*)&Erb[off] = load8(&Er[off]);
    return;
  }
  __shared__ __bf16 tile[32][33];
  int c0 = (blockIdx.x % 96) * 32, r0 = (blockIdx.x / 96) * 32;
#pragma unroll
  for (int i = ty; i < 32; i += 8)
    tile[i][tx] = (__bf16)Wqkv[(size_t)(r0 + i) * 3072 + c0 + tx];
  __syncthreads();
#pragma unroll
  for (int i = ty; i < 32; i += 8)
    WqkvT[(size_t)(c0 + i) * 1024 + r0 + tx] = tile[tx][i];
}

// ------------------------------------------------------- transpose-convert
// src fp32 [R][C] -> dst bf16 [C][R]. 32x32 tiles, block (32,8). (Wproj)
__global__ void tconv_k(const float* __restrict__ src, __bf16* __restrict__ dst,
                        int R, int C) {
  __shared__ __bf16 tile[32][33];
  int c0 = blockIdx.x * 32, r0 = blockIdx.y * 32;
  int tx = threadIdx.x, ty = threadIdx.y;
#pragma unroll
  for (int i = ty; i < 32; i += 8)
    tile[i][tx] = (__bf16)src[(size_t)(r0 + i) * C + c0 + tx];
  __syncthreads();
#pragma unroll
  for (int i = ty; i < 32; i += 8)
    dst[(size_t)(c0 + i) * R + r0 + tx] = tile[tx][i];
}

// ---------------------------------------------------------------- GEMM1 (m97)
// qkv = xb[4096,1024] @ WqkvT[3072,1024]^T + bias. All-bf16 DMA staging.
// 128x128 tile, BK=64 (half the barrier pairs vs BK=32 — barrier drain is
// the structural cost of this K-loop). LDS 32 KB -> >=5 blocks/CU capacity.
__global__ __launch_bounds__(256) void gemm_qkv_k(
    const __bf16* __restrict__ A, const __bf16* __restrict__ Bt,
    const float* __restrict__ bias, __bf16* __restrict__ Qo,
    __bf16* __restrict__ Ko, __bf16* __restrict__ Vto) {
  const int K = 1024;
  __shared__ __align__(16) __bf16 As[128 * 64];  // [m][k], unpadded (DMA)
  __shared__ __align__(16) __bf16 Bs[128 * 64];  // [n][k], unpadded (DMA)
  int t = threadIdx.x;
  int wave = t >> 6, lane = t & 63, qd = lane >> 4, lr = lane & 15;
  int m0 = blockIdx.y * 128, n0 = blockIdx.x * 128;
  int wm = (wave >> 1) * 64, wn = (wave & 1) * 64;
  f32x4 acc[4][4] = {};
  // DMA group = 8 rows x 64 k (1024B). Lane l -> row (l>>3), k-col (l&7)*8.
  int srow = lane >> 3, sch = (lane & 7) * 8;
  const __bf16* Ab[4];
  const __bf16* Bb[4];
#pragma unroll
  for (int c = 0; c < 4; c++) {
    Ab[c] = A + (size_t)(m0 + (wave * 4 + c) * 8 + srow) * K + sch;
    Bb[c] = Bt + (size_t)(n0 + (wave * 4 + c) * 8 + srow) * K + sch;
  }
  for (int k0 = 0; k0 < K; k0 += 64) {
    __syncthreads();
#pragma unroll
    for (int c = 0; c < 4; c++) {
      async_ld16(&As[(wave * 4 + c) * 512], Ab[c] + k0);
      async_ld16(&Bs[(wave * 4 + c) * 512], Bb[c] + k0);
    }
    __syncthreads();
#pragma unroll
    for (int kc = 0; kc < 2; kc++) {
      bf16x8 af[4], bfr[4];
#pragma unroll
      for (int mt = 0; mt < 4; mt++)
        af[mt] = *(const bf16x8*)&As[(wm + mt * 16 + lr) * 64 + kc * 32 + qd * 8];
#pragma unroll
      for (int nt = 0; nt < 4; nt++)
        bfr[nt] = *(const bf16x8*)&Bs[(wn + nt * 16 + lr) * 64 + kc * 32 + qd * 8];
#pragma unroll
      for (int mt = 0; mt < 4; mt++)
#pragma unroll
        for (int nt = 0; nt < 4; nt++)
          acc[mt][nt] = __builtin_amdgcn_mfma_f32_16x16x32_bf16(af[mt], bfr[nt],
                                                                acc[mt][nt], 0, 0, 0);
    }
  }
  // C/D: col = lane&15, row = quad*4 + reg
  float bvv[4];
#pragma unroll
  for (int nt = 0; nt < 4; nt++) bvv[nt] = bias[n0 + wn + nt * 16 + lr];
#pragma unroll
  for (int mt = 0; mt < 4; mt++)
#pragma unroll
    for (int nt = 0; nt < 4; nt++)
#pragma unroll
      for (int r = 0; r < 4; r++) {
        int row = m0 + wm + mt * 16 + qd * 4 + r;
        int col = n0 + wn + nt * 16 + lr;
        __bf16 bb = (__bf16)(acc[mt][nt][r] + bvv[nt]);
        int b = row >> 11, l = row & 2047;
        int h = (col >> 6) & 15, d = col & 63;
        if (col < DD) {
          Qo[(((size_t)(b * NHH + h)) * LL + l) * HSS + d] = bb;
        } else if (col < 2 * DD) {
          Ko[(((size_t)(b * NHH + h)) * LL + l) * HSS + d] = bb;
        } else {
          Vto[(((size_t)(b * NHH + h)) * HSS + d) * LL + l] = bb;  // V^T scatter
        }
      }
}

// ---------------------------------------------------------------- GEMM2 (proj)
// out[4096,1024] = Y[4096,1024](bf16) @ WprojT[1024,1024](bf16)^T + bproj.
// All-DMA staging, BK=64. 128x64 tile, grid 512 = 2/CU.
__global__ __launch_bounds__(256) void gemm_proj_k(
    const __bf16* __restrict__ A, const __bf16* __restrict__ Bt,
    const float* __restrict__ bias, float* __restrict__ out) {
  const int K = 1024, N = 1024;
  __shared__ __align__(16) __bf16 As[128 * 64];  // [m][k], unpadded (DMA)
  __shared__ __align__(16) __bf16 Bs[64 * 64];   // [n][k], unpadded (DMA)
  int t = threadIdx.x;
  int wave = t >> 6, lane = t & 63, qd = lane >> 4, lr = lane & 15;
  int m0 = blockIdx.y * 128, n0 = blockIdx.x * 64;
  int wm = (wave >> 1) * 64, wn = (wave & 1) * 32;
  f32x4 acc[4][2] = {};
  int srow = lane >> 3, sch = (lane & 7) * 8;
  const __bf16* Ab[4];
  const __bf16* Bb[2];
#pragma unroll
  for (int c = 0; c < 4; c++)
    Ab[c] = A + (size_t)(m0 + (wave * 4 + c) * 8 + srow) * K + sch;
#pragma unroll
  for (int c = 0; c < 2; c++)
    Bb[c] = Bt + (size_t)(n0 + (wave * 2 + c) * 8 + srow) * K + sch;

  for (int k0 = 0; k0 < K; k0 += 64) {
    __syncthreads();
#pragma unroll
    for (int c = 0; c < 4; c++)
      async_ld16(&As[(wave * 4 + c) * 512], Ab[c] + k0);
#pragma unroll
    for (int c = 0; c < 2; c++)
      async_ld16(&Bs[(wave * 2 + c) * 512], Bb[c] + k0);
    __syncthreads();
#pragma unroll
    for (int kc = 0; kc < 2; kc++) {
      bf16x8 af[4], bfr[2];
#pragma unroll
      for (int mt = 0; mt < 4; mt++)
        af[mt] = *(const bf16x8*)&As[(wm + mt * 16 + lr) * 64 + kc * 32 + qd * 8];
#pragma unroll
      for (int nt = 0; nt < 2; nt++)
        bfr[nt] = *(const bf16x8*)&Bs[(wn + nt * 16 + lr) * 64 + kc * 32 + qd * 8];
#pragma unroll
      for (int mt = 0; mt < 4; mt++)
#pragma unroll
        for (int nt = 0; nt < 2; nt++)
          acc[mt][nt] = __builtin_amdgcn_mfma_f32_16x16x32_bf16(af[mt], bfr[nt],
                                                                acc[mt][nt], 0, 0, 0);
    }
  }
  float bvv[2];
#pragma unroll
  for (int nt = 0; nt < 2; nt++) bvv[nt] = bias[n0 + wn + nt * 16 + lr];
#pragma unroll
  for (int mt = 0; mt < 4; mt++)
#pragma unroll
    for (int nt = 0; nt < 2; nt++)
#pragma unroll
      for (int r = 0; r < 4; r++) {
        int row = m0 + wm + mt * 16 + qd * 4 + r;
        int col = n0 + wn + nt * 16 + lr;
        out[(size_t)row * N + col] = acc[mt][nt][r] + bvv[nt];
      }
}

// ---------------------------------------------------------------- flash attn
// Srel[i,j] = q_i . Er[L-1-i+j]. Grid (bh=32, 32 tiles), heavy-first.
// bounds (256,3): (256,4) squeezed VGPR 72->64 and pushed the ~40-VGPR
// ef[5][2] Er prefetch toward its use, exposing L2 latency (round-10 -18%).
// Ones-column l-accumulation B-frag from registers (lane lr==0 supplies 1.0).
__global__ __launch_bounds__(256, 3) void flash_k(
    const __bf16* __restrict__ Qg, const __bf16* __restrict__ Kg,
    const __bf16* __restrict__ Vtg, const __bf16* __restrict__ Erb,
    __bf16* __restrict__ Yg) {
  __shared__ __align__(16) __bf16 Kld[64 * 72];    // [j][d]
  __shared__ __align__(16) __bf16 Vld[64 * 72];    // [d][j]
  __shared__ __align__(16) __bf16 Pball[4][16 * 72];

  int bh = blockIdx.x;
  int i0 = (31 - (int)blockIdx.y) * 64;  // heavy tiles dispatch first
  const __bf16* Qh = Qg + (size_t)bh * LL * HSS;
  const __bf16* Kh = Kg + (size_t)bh * LL * HSS;
  const __bf16* Vth = Vtg + (size_t)bh * HSS * LL;
  int b = bh >> 4, h = bh & 15;
  int t = threadIdx.x, wave = t >> 6, lane = t & 63, qd = lane >> 4, lr = lane & 15;
  __bf16* Pb = &Pball[wave][0];
  int cbase = 48 - wave * 16;

  // ones-column B-frag: B[k][n]=1 iff n==0 -> lane lr==0 supplies 1.0
  bf16x8 bones;
#pragma unroll
  for (int q = 0; q < 8; q++) bones[q] = (lr == 0) ? (__bf16)1.f : (__bf16)0.f;

  int jj = t >> 2, hf = t & 3;

  bf16x8 aq[2];
  {
    const __bf16* qrow = Qh + (size_t)(i0 + wave * 16 + lr) * HSS + qd * 8;
    aq[0] = *(const bf16x8*)qrow;
    aq[1] = *(const bf16x8*)(qrow + 32);
  }
  f32x4 oacc[5] = {};  // [0..3]=O d-tiles, [4]=l in local col 0

  bf16x8 kr0, kr1, vr0, vr1;
  auto prefetch = [&](int j0) {
    kr0 = *(const bf16x8*)&Kh[(size_t)(j0 + jj) * HSS + hf * 16];
    kr1 = *(const bf16x8*)&Kh[(size_t)(j0 + jj) * HSS + hf * 16 + 8];
    vr0 = *(const bf16x8*)&Vth[(size_t)jj * LL + j0 + hf * 16];
    vr1 = *(const bf16x8*)&Vth[(size_t)jj * LL + j0 + hf * 16 + 8];
  };
  prefetch(0);

  for (int j0 = 0; j0 <= i0; j0 += 64) {
    __syncthreads();
    *(bf16x8*)&Kld[jj * 72 + hf * 16] = kr0;
    *(bf16x8*)&Kld[jj * 72 + hf * 16 + 8] = kr1;
    *(bf16x8*)&Vld[jj * 72 + hf * 16] = vr0;
    *(bf16x8*)&Vld[jj * 72 + hf * 16 + 8] = vr1;
    __syncthreads();
    if (j0 + 64 <= i0) prefetch(j0 + 64);

    // Er B-frags direct from global bf16 (window L1/L2-hot); issued here,
    // first used after QK -> latency overlapped.
    bf16x8 ef[5][2];
    int ebase = LL - 64 - i0 + j0 + cbase;
#pragma unroll
    for (int ct = 0; ct < 5; ct++) {
      int e = ebase + ct * 16 + lr;
      e = (e < LL) ? e : (LL - 1);  // clamped rows feed only masked entries
#pragma unroll
      for (int kc = 0; kc < 2; kc++)
        ef[ct][kc] = *(const bf16x8*)&Erb[(size_t)e * HSS + kc * 32 + qd * 8];
    }

    // QK^T: 4 col-tiles x 2 k-chunks (LDS)
    f32x4 sacc[4] = {};
#pragma unroll
    for (int ct = 0; ct < 4; ct++)
#pragma unroll
      for (int kc = 0; kc < 2; kc++) {
        bf16x8 bk = *(const bf16x8*)&Kld[(ct * 16 + lr) * 72 + kc * 32 + qd * 8];
        sacc[ct] = __builtin_amdgcn_mfma_f32_16x16x32_bf16(aq[kc], bk, sacc[ct], 0, 0, 0);
      }
    // rel: 5 col-tiles over the 80-col window, B-frags from registers
    f32x4 racc[5] = {};
#pragma unroll
    for (int ct = 0; ct < 5; ct++)
#pragma unroll
      for (int kc = 0; kc < 2; kc++)
        racc[ct] = __builtin_amdgcn_mfma_f32_16x16x32_bf16(aq[kc], ef[ct][kc],
                                                           racc[ct], 0, 0, 0);

    // Rel diagonal gather via shuffles (round-4-verified), p = exp(s).
#pragma unroll
    for (int r = 0; r < 4; r++) {
      int tr = qd * 4 + r;
      int base = 15 - tr + lr;
      int src = qd * 16 + (base & 15);
      int hi = base >> 4;
      float sh[5];
#pragma unroll
      for (int ct = 0; ct < 5; ct++) sh[ct] = __shfl(racc[ct][r], src, 64);
      int gi = i0 + wave * 16 + tr;
#pragma unroll
      for (int ct2 = 0; ct2 < 4; ct2++) {
        float rel = hi ? sh[ct2 + 1] : sh[ct2];
        float s = (sacc[ct2][r] + rel) * 0.125f;
        int gj = j0 + ct2 * 16 + lr;
        float p = (gj <= gi) ? __expf(s) : 0.f;
        Pb[tr * 72 + ct2 * 16 + lr] = (__bf16)p;
      }
    }

    // O += P V (dt 0..3, LDS V-frags), l += P (ones B-frag from registers).
    bf16x8 ap0 = *(const bf16x8*)&Pb[lr * 72 + qd * 8];
    bf16x8 ap1 = *(const bf16x8*)&Pb[lr * 72 + 32 + qd * 8];
#pragma unroll
    for (int dt = 0; dt < 4; dt++) {
      bf16x8 bv0 = *(const bf16x8*)&Vld[(dt * 16 + lr) * 72 + qd * 8];
      bf16x8 bv1 = *(const bf16x8*)&Vld[(dt * 16 + lr) * 72 + 32 + qd * 8];
      oacc[dt] = __builtin_amdgcn_mfma_f32_16x16x32_bf16(ap0, bv0, oacc[dt], 0, 0, 0);
      oacc[dt] = __builtin_amdgcn_mfma_f32_16x16x32_bf16(ap1, bv1, oacc[dt], 0, 0, 0);
    }
    oacc[4] = __builtin_amdgcn_mfma_f32_16x16x32_bf16(ap0, bones, oacc[4], 0, 0, 0);
    oacc[4] = __builtin_amdgcn_mfma_f32_16x16x32_bf16(ap1, bones, oacc[4], 0, 0, 0);
  }

#pragma unroll
  for (int r = 0; r < 4; r++) {
    float lv = __shfl(oacc[4][r], qd * 16, 64);
    float inv = 1.f / lv;
    int l = i0 + wave * 16 + qd * 4 + r;
#pragma unroll
    for (int dt = 0; dt < 4; dt++) {
      int d = dt * 16 + lr;
      Yg[((size_t)(b * LL) + l) * DD + h * HSS + d] = (__bf16)(oacc[dt][r] * inv);
    }
  }
}

// ---------------------------------------------------------------- launch
extern "C" void kernel_launch(void* const* d_in, const int* in_sizes, int n_in,
                              void* d_out, int out_size, void* d_ws, size_t ws_size,
                              hipStream_t stream) {
  // Reference dtypes: ALL inputs fp32, output fp32 (confirmed round 4).
  const float* x = (const float*)d_in[0];
  const float* Wqkv = (const float*)d_in[1];
  const float* bqkv = (const float*)d_in[2];
  const float* Wproj = (const float*)d_in[3];
  const float* bproj = (const float*)d_in[4];
  const float* Er = (const float*)d_in[5];
  float* out = (float*)d_out;

  if (ws_size < 4u * 8388608u) return;  // 33.55 MB, confirmed present

  uint8_t* w = (uint8_t*)d_ws;
  __bf16* Q = (__bf16*)w;  w += (size_t)BB * NHH * LL * HSS * 2;
  __bf16* Kt = (__bf16*)w; w += (size_t)BB * NHH * LL * HSS * 2;
  __bf16* Vt = (__bf16*)w; w += (size_t)BB * NHH * LL * HSS * 2;
  __bf16* Y = (__bf16*)w;  w += (size_t)BB * LL * DD * 2;

  // d_out scratch overlay (16.78 MB, all dead before gemm_proj writes it):
  //   WqkvT 6.29 MB @0 (dead after gemm_qkv), xb 8.39 MB @6.29M (dead after
  //   gemm_qkv), Erb 0.26 MB @14.68M (dead after flash).
  __bf16* WqkvT = (__bf16*)d_out;
  __bf16* xb = (__bf16*)((uint8_t*)d_out + (size_t)3072 * 1024 * 2);
  __bf16* Erb = (__bf16*)((uint8_t*)d_out + (size_t)3072 * 1024 * 2 + (size_t)4096 * 1024 * 2);
  // WprojT (2.1 MB) -> Q region, written AFTER flash (Q dead by then);
  // NOT in d_out: gemm_proj writes d_out while reading WprojT (would race).
  __bf16* WprojT = Q;

  prep_k<<<dim3(3072, 1, 3), dim3(32, 8), 0, stream>>>(Wqkv, x, Er, WqkvT, xb, Erb);
  gemm_qkv_k<<<dim3(3072 / 128, 4096 / 128), 256, 0, stream>>>(
      xb, WqkvT, bqkv, Q, Kt, Vt);
  flash_k<<<dim3(BB * NHH, 32), 256, 0, stream>>>(Q, Kt, Vt, Erb, Y);
  tconv_k<<<dim3(1024 / 32, 1024 / 32), dim3(32, 8), 0, stream>>>(Wproj, WprojT, 1024, 1024);
  gemm_proj_k<<<dim3(1024 / 64, 4096 / 128), 256, 0, stream>>>(Y, WprojT, bproj, out);
}

// Round 12
// 250.665 us; speedup vs baseline: 1.0907x; 1.0907x over previous
//
#include <hip/hip_runtime.h>
#include <stdint.h>

#define BB 2
#define LL 2048
#define DD 1024
#define NHH 16
#define HSS 64

typedef __bf16 bf16x8 __attribute__((ext_vector_type(8)));
typedef float f32x4 __attribute__((ext_vector_type(4)));

// Load 8 consecutive elements as bf16x8, converting from fp32 if needed.
__device__ __forceinline__ bf16x8 load8(const float* p) {
  float4 f0 = *(const float4*)p;
  float4 f1 = *(const float4*)(p + 4);
  bf16x8 v;
  v[0] = (__bf16)f0.x; v[1] = (__bf16)f0.y; v[2] = (__bf16)f0.z; v[3] = (__bf16)f0.w;
  v[4] = (__bf16)f1.x; v[5] = (__bf16)f1.y; v[6] = (__bf16)f1.z; v[7] = (__bf16)f1.w;
  return v;
}
__device__ __forceinline__ bf16x8 load8(const __bf16* p) {
  return *(const bf16x8*)p;
}

// Async global->LDS DMA, 16B/lane. LDS dest WAVE-UNIFORM base; HW writes
// lane l at base + l*16 (m97-verified). Target LDS must be unpadded.
__device__ __forceinline__ void async_ld16(__bf16* lds_uniform_base,
                                           const __bf16* gptr_per_lane) {
  __builtin_amdgcn_global_load_lds(
      (const __attribute__((address_space(1))) void*)gptr_per_lane,
      (__attribute__((address_space(3))) void*)lds_uniform_base, 16, 0, 0);
}

// ---------------------------------------------------------------- prep (fused)
// z=0: Wqkv fp32 [1024][3072] -> WqkvT bf16 [3072][1024]   (3072 tiles)
// z=1: x fp32 -> xb bf16 elementwise (4.19M elems)          (2048 blocks)
// z=2: Er fp32 -> Erb bf16 elementwise (131072 elems)       (64 blocks)
__global__ void prep_k(const float* __restrict__ Wqkv, const float* __restrict__ x,
                       const float* __restrict__ Er, __bf16* __restrict__ WqkvT,
                       __bf16* __restrict__ xb, __bf16* __restrict__ Erb) {
  int tx = threadIdx.x, ty = threadIdx.y;
  int tid = ty * 32 + tx;
  if (blockIdx.z == 1) {
    if (blockIdx.x >= 2048) return;
    size_t off = ((size_t)blockIdx.x * 256 + tid) * 8;
    *(bf16x8*)&xb[off] = load8(&x[off]);
    return;
  }
  if (blockIdx.z == 2) {
    if (blockIdx.x >= 64) return;
    size_t off = ((size_t)blockIdx.x * 256 + tid) * 8;
    *(bf16x8*)&Erb[off] = load8(&Er[off]);
    return;
  }
  __shared__ __bf16 tile[32][33];
  int c0 = (blockIdx.x % 96) * 32, r0 = (blockIdx.x / 96) * 32;
#pragma unroll
  for (int i = ty; i < 32; i += 8)
    tile[i][tx] = (__bf16)Wqkv[(size_t)(r0 + i) * 3072 + c0 + tx];
  __syncthreads();
#pragma unroll
  for (int i = ty; i < 32; i += 8)
    WqkvT[(size_t)(c0 + i) * 1024 + r0 + tx] = tile[tx][i];
}

// ------------------------------------------------------- transpose-convert
// src fp32 [R][C] -> dst bf16 [C][R]. 32x32 tiles, block (32,8). (Wproj)
__global__ void tconv_k(const float* __restrict__ src, __bf16* __restrict__ dst,
                        int R, int C) {
  __shared__ __bf16 tile[32][33];
  int c0 = blockIdx.x * 32, r0 = blockIdx.y * 32;
  int tx = threadIdx.x, ty = threadIdx.y;
#pragma unroll
  for (int i = ty; i < 32; i += 8)
    tile[i][tx] = (__bf16)src[(size_t)(r0 + i) * C + c0 + tx];
  __syncthreads();
#pragma unroll
  for (int i = ty; i < 32; i += 8)
    dst[(size_t)(c0 + i) * R + r0 + tx] = tile[tx][i];
}

// ---------------------------------------------------------------- GEMM1 (m97)
// qkv = xb[4096,1024] @ WqkvT[3072,1024]^T + bias. BK=32 (R10-measured best).
__global__ __launch_bounds__(256) void gemm_qkv_k(
    const __bf16* __restrict__ A, const __bf16* __restrict__ Bt,
    const float* __restrict__ bias, __bf16* __restrict__ Qo,
    __bf16* __restrict__ Ko, __bf16* __restrict__ Vto) {
  const int K = 1024;
  __shared__ __align__(16) __bf16 As[128 * 32];  // [m][k], unpadded (DMA)
  __shared__ __align__(16) __bf16 Bs[128 * 32];  // [n][k], unpadded (DMA)
  int t = threadIdx.x;
  int wave = t >> 6, lane = t & 63, qd = lane >> 4, lr = lane & 15;
  int m0 = blockIdx.y * 128, n0 = blockIdx.x * 128;
  int wm = (wave >> 1) * 64, wn = (wave & 1) * 64;
  f32x4 acc[4][4] = {};
  int srow = lane >> 2, sch = (lane & 3) * 8;
  const __bf16* Ab[2];
  const __bf16* Bb[2];
#pragma unroll
  for (int c = 0; c < 2; c++) {
    Ab[c] = A + (size_t)(m0 + (wave * 2 + c) * 16 + srow) * K + sch;
    Bb[c] = Bt + (size_t)(n0 + (wave * 2 + c) * 16 + srow) * K + sch;
  }
  for (int k0 = 0; k0 < K; k0 += 32) {
    __syncthreads();
#pragma unroll
    for (int c = 0; c < 2; c++) {
      async_ld16(&As[(wave * 2 + c) * 512], Ab[c] + k0);
      async_ld16(&Bs[(wave * 2 + c) * 512], Bb[c] + k0);
    }
    __syncthreads();
    bf16x8 af[4], bfr[4];
#pragma unroll
    for (int mt = 0; mt < 4; mt++)
      af[mt] = *(const bf16x8*)&As[(wm + mt * 16 + lr) * 32 + qd * 8];
#pragma unroll
    for (int nt = 0; nt < 4; nt++)
      bfr[nt] = *(const bf16x8*)&Bs[(wn + nt * 16 + lr) * 32 + qd * 8];
#pragma unroll
    for (int mt = 0; mt < 4; mt++)
#pragma unroll
      for (int nt = 0; nt < 4; nt++)
        acc[mt][nt] = __builtin_amdgcn_mfma_f32_16x16x32_bf16(af[mt], bfr[nt],
                                                              acc[mt][nt], 0, 0, 0);
  }
  // C/D: col = lane&15, row = quad*4 + reg
  float bvv[4];
#pragma unroll
  for (int nt = 0; nt < 4; nt++) bvv[nt] = bias[n0 + wn + nt * 16 + lr];
#pragma unroll
  for (int mt = 0; mt < 4; mt++)
#pragma unroll
    for (int nt = 0; nt < 4; nt++)
#pragma unroll
      for (int r = 0; r < 4; r++) {
        int row = m0 + wm + mt * 16 + qd * 4 + r;
        int col = n0 + wn + nt * 16 + lr;
        __bf16 bb = (__bf16)(acc[mt][nt][r] + bvv[nt]);
        int b = row >> 11, l = row & 2047;
        int h = (col >> 6) & 15, d = col & 63;
        if (col < DD) {
          Qo[(((size_t)(b * NHH + h)) * LL + l) * HSS + d] = bb;
        } else if (col < 2 * DD) {
          Ko[(((size_t)(b * NHH + h)) * LL + l) * HSS + d] = bb;
        } else {
          Vto[(((size_t)(b * NHH + h)) * HSS + d) * LL + l] = bb;  // V^T scatter
        }
      }
}

// ---------------------------------------------------------------- GEMM2 (proj)
// out = Y[4096,1024](bf16) @ WprojT^T + bproj. BK=32 all-DMA (R10 best).
__global__ __launch_bounds__(256) void gemm_proj_k(
    const __bf16* __restrict__ A, const __bf16* __restrict__ Bt,
    const float* __restrict__ bias, float* __restrict__ out) {
  const int K = 1024, N = 1024;
  __shared__ __align__(16) __bf16 As[128 * 32];  // [m][k], unpadded (DMA)
  __shared__ __align__(16) __bf16 Bs[64 * 32];   // [n][k], unpadded (DMA)
  int t = threadIdx.x;
  int wave = t >> 6, lane = t & 63, qd = lane >> 4, lr = lane & 15;
  int m0 = blockIdx.y * 128, n0 = blockIdx.x * 64;
  int wm = (wave >> 1) * 64, wn = (wave & 1) * 32;
  f32x4 acc[4][2] = {};
  int srow = lane >> 2, sch = (lane & 3) * 8;
  const __bf16* Ab[2];
  const __bf16* Bb;
#pragma unroll
  for (int c = 0; c < 2; c++)
    Ab[c] = A + (size_t)(m0 + (wave * 2 + c) * 16 + srow) * K + sch;
  Bb = Bt + (size_t)(n0 + wave * 16 + srow) * K + sch;

  for (int k0 = 0; k0 < K; k0 += 32) {
    __syncthreads();
#pragma unroll
    for (int c = 0; c < 2; c++)
      async_ld16(&As[(wave * 2 + c) * 512], Ab[c] + k0);
    async_ld16(&Bs[wave * 512], Bb + k0);
    __syncthreads();
    bf16x8 af[4], bfr[2];
#pragma unroll
    for (int mt = 0; mt < 4; mt++)
      af[mt] = *(const bf16x8*)&As[(wm + mt * 16 + lr) * 32 + qd * 8];
#pragma unroll
    for (int nt = 0; nt < 2; nt++)
      bfr[nt] = *(const bf16x8*)&Bs[(wn + nt * 16 + lr) * 32 + qd * 8];
#pragma unroll
    for (int mt = 0; mt < 4; mt++)
#pragma unroll
      for (int nt = 0; nt < 2; nt++)
        acc[mt][nt] = __builtin_amdgcn_mfma_f32_16x16x32_bf16(af[mt], bfr[nt],
                                                              acc[mt][nt], 0, 0, 0);
  }
  float bvv[2];
#pragma unroll
  for (int nt = 0; nt < 2; nt++) bvv[nt] = bias[n0 + wn + nt * 16 + lr];
#pragma unroll
  for (int mt = 0; mt < 4; mt++)
#pragma unroll
    for (int nt = 0; nt < 2; nt++)
#pragma unroll
      for (int r = 0; r < 4; r++) {
        int row = m0 + wm + mt * 16 + qd * 4 + r;
        int col = n0 + wn + nt * 16 + lr;
        out[(size_t)row * N + col] = acc[mt][nt][r] + bvv[nt];
      }
}

// ---------------------------------------------------------------- flash attn
// SPLIT-K over j (z=2 halves): unnormalized softmax makes partials ADDITIVE
// (no max/alpha merge): Y = (O0+O1)/(l0+l1). Each half-block writes its
// unnormalized O (bf16) and l (fp32) exactly once; combine_k sums+divides.
// Grid (bh=32, tile=32 heavy-first, half=2) = 2048 blocks, max 16 iters each.
__global__ __launch_bounds__(256, 3) void flash_k(
    const __bf16* __restrict__ Qg, const __bf16* __restrict__ Kg,
    const __bf16* __restrict__ Vtg, const __bf16* __restrict__ Erb,
    __bf16* __restrict__ Po0, __bf16* __restrict__ Po1,
    float* __restrict__ Lp0, float* __restrict__ Lp1) {
  __shared__ __align__(16) __bf16 Kld[64 * 72];    // [j][d]
  __shared__ __align__(16) __bf16 Vld[64 * 72];    // [d][j]
  __shared__ __align__(16) __bf16 Pball[4][16 * 72];

  int bh = blockIdx.x;
  int tile = 31 - (int)blockIdx.y;  // heavy tiles dispatch first
  int i0 = tile * 64;
  int niter = tile + 1;
  int mid = (niter + 1) >> 1;
  int it0 = (blockIdx.z == 0) ? 0 : mid;
  int it1 = (blockIdx.z == 0) ? mid : niter;
  const __bf16* Qh = Qg + (size_t)bh * LL * HSS;
  const __bf16* Kh = Kg + (size_t)bh * LL * HSS;
  const __bf16* Vth = Vtg + (size_t)bh * HSS * LL;
  int b = bh >> 4, h = bh & 15;
  int t = threadIdx.x, wave = t >> 6, lane = t & 63, qd = lane >> 4, lr = lane & 15;
  __bf16* Pb = &Pball[wave][0];
  int cbase = 48 - wave * 16;

  // ones-column B-frag: B[k][n]=1 iff n==0 -> lane lr==0 supplies 1.0
  bf16x8 bones;
#pragma unroll
  for (int q = 0; q < 8; q++) bones[q] = (lr == 0) ? (__bf16)1.f : (__bf16)0.f;

  int jj = t >> 2, hf = t & 3;

  bf16x8 aq[2];
  {
    const __bf16* qrow = Qh + (size_t)(i0 + wave * 16 + lr) * HSS + qd * 8;
    aq[0] = *(const bf16x8*)qrow;
    aq[1] = *(const bf16x8*)(qrow + 32);
  }
  f32x4 oacc[5] = {};  // [0..3]=O d-tiles, [4]=l in local col 0

  bf16x8 kr0, kr1, vr0, vr1;
  auto prefetch = [&](int j0) {
    kr0 = *(const bf16x8*)&Kh[(size_t)(j0 + jj) * HSS + hf * 16];
    kr1 = *(const bf16x8*)&Kh[(size_t)(j0 + jj) * HSS + hf * 16 + 8];
    vr0 = *(const bf16x8*)&Vth[(size_t)jj * LL + j0 + hf * 16];
    vr1 = *(const bf16x8*)&Vth[(size_t)jj * LL + j0 + hf * 16 + 8];
  };
  if (it0 < it1) prefetch(it0 * 64);

  for (int it = it0; it < it1; ++it) {
    int j0 = it * 64;
    __syncthreads();
    *(bf16x8*)&Kld[jj * 72 + hf * 16] = kr0;
    *(bf16x8*)&Kld[jj * 72 + hf * 16 + 8] = kr1;
    *(bf16x8*)&Vld[jj * 72 + hf * 16] = vr0;
    *(bf16x8*)&Vld[jj * 72 + hf * 16 + 8] = vr1;
    __syncthreads();
    if (it + 1 < it1) prefetch((it + 1) * 64);

    // Er B-frags direct from global bf16 (window L1/L2-hot); issued here,
    // first used after QK -> latency overlapped.
    bf16x8 ef[5][2];
    int ebase = LL - 64 - i0 + j0 + cbase;
#pragma unroll
    for (int ct = 0; ct < 5; ct++) {
      int e = ebase + ct * 16 + lr;
      e = (e < LL) ? e : (LL - 1);  // clamped rows feed only masked entries
#pragma unroll
      for (int kc = 0; kc < 2; kc++)
        ef[ct][kc] = *(const bf16x8*)&Erb[(size_t)e * HSS + kc * 32 + qd * 8];
    }

    // QK^T: 4 col-tiles x 2 k-chunks (LDS)
    f32x4 sacc[4] = {};
#pragma unroll
    for (int ct = 0; ct < 4; ct++)
#pragma unroll
      for (int kc = 0; kc < 2; kc++) {
        bf16x8 bk = *(const bf16x8*)&Kld[(ct * 16 + lr) * 72 + kc * 32 + qd * 8];
        sacc[ct] = __builtin_amdgcn_mfma_f32_16x16x32_bf16(aq[kc], bk, sacc[ct], 0, 0, 0);
      }
    // rel: 5 col-tiles over the 80-col window, B-frags from registers
    f32x4 racc[5] = {};
#pragma unroll
    for (int ct = 0; ct < 5; ct++)
#pragma unroll
      for (int kc = 0; kc < 2; kc++)
        racc[ct] = __builtin_amdgcn_mfma_f32_16x16x32_bf16(aq[kc], ef[ct][kc],
                                                           racc[ct], 0, 0, 0);

    // Rel diagonal gather via shuffles (round-4-verified), p = exp(s).
#pragma unroll
    for (int r = 0; r < 4; r++) {
      int tr = qd * 4 + r;
      int base = 15 - tr + lr;
      int src = qd * 16 + (base & 15);
      int hi = base >> 4;
      float sh[5];
#pragma unroll
      for (int ct = 0; ct < 5; ct++) sh[ct] = __shfl(racc[ct][r], src, 64);
      int gi = i0 + wave * 16 + tr;
#pragma unroll
      for (int ct2 = 0; ct2 < 4; ct2++) {
        float rel = hi ? sh[ct2 + 1] : sh[ct2];
        float s = (sacc[ct2][r] + rel) * 0.125f;
        int gj = j0 + ct2 * 16 + lr;
        float p = (gj <= gi) ? __expf(s) : 0.f;
        Pb[tr * 72 + ct2 * 16 + lr] = (__bf16)p;
      }
    }

    // O += P V (dt 0..3, LDS V-frags), l += P (ones B-frag from registers).
    bf16x8 ap0 = *(const bf16x8*)&Pb[lr * 72 + qd * 8];
    bf16x8 ap1 = *(const bf16x8*)&Pb[lr * 72 + 32 + qd * 8];
#pragma unroll
    for (int dt = 0; dt < 4; dt++) {
      bf16x8 bv0 = *(const bf16x8*)&Vld[(dt * 16 + lr) * 72 + qd * 8];
      bf16x8 bv1 = *(const bf16x8*)&Vld[(dt * 16 + lr) * 72 + 32 + qd * 8];
      oacc[dt] = __builtin_amdgcn_mfma_f32_16x16x32_bf16(ap0, bv0, oacc[dt], 0, 0, 0);
      oacc[dt] = __builtin_amdgcn_mfma_f32_16x16x32_bf16(ap1, bv1, oacc[dt], 0, 0, 0);
    }
    oacc[4] = __builtin_amdgcn_mfma_f32_16x16x32_bf16(ap0, bones, oacc[4], 0, 0, 0);
    oacc[4] = __builtin_amdgcn_mfma_f32_16x16x32_bf16(ap1, bones, oacc[4], 0, 0, 0);
  }

  // epilogue: write UNNORMALIZED partial O (bf16) and partial l (fp32).
  __bf16* Po = (blockIdx.z == 0) ? Po0 : Po1;
  float* Lp = (blockIdx.z == 0) ? Lp0 : Lp1;
#pragma unroll
  for (int r = 0; r < 4; r++) {
    int l = i0 + wave * 16 + qd * 4 + r;
    if (lr == 0) Lp[(size_t)bh * LL + l] = oacc[4][r];  // col-0 lives in lr==0
#pragma unroll
    for (int dt = 0; dt < 4; dt++) {
      int d = dt * 16 + lr;
      Po[((size_t)(b * LL) + l) * DD + h * HSS + d] = (__bf16)oacc[dt][r];
    }
  }
}

// ---------------------------------------------------------------- combine
// Y = (Po0 + Po1) / (Lp0 + Lp1), elementwise with per-row l. 2048 blocks.
__global__ void combine_k(const __bf16* __restrict__ Po0,
                          const __bf16* __restrict__ Po1,
                          const float* __restrict__ Lp0,
                          const float* __restrict__ Lp1,
                          __bf16* __restrict__ Y) {
  size_t f = ((size_t)blockIdx.x * 256 + threadIdx.x) * 8;
  int dfull = (int)(f & 1023);
  int h = dfull >> 6;
  int l = (int)((f >> 10) & 2047);
  int b = (int)(f >> 21);
  size_t lidx = ((size_t)(b * NHH + h)) * LL + l;
  float linv = 1.f / (Lp0[lidx] + Lp1[lidx]);
  bf16x8 a = *(const bf16x8*)&Po0[f];
  bf16x8 c = *(const bf16x8*)&Po1[f];
  bf16x8 o;
#pragma unroll
  for (int q = 0; q < 8; q++)
    o[q] = (__bf16)(((float)a[q] + (float)c[q]) * linv);
  *(bf16x8*)&Y[f] = o;
}

// ---------------------------------------------------------------- launch
extern "C" void kernel_launch(void* const* d_in, const int* in_sizes, int n_in,
                              void* d_out, int out_size, void* d_ws, size_t ws_size,
                              hipStream_t stream) {
  // Reference dtypes: ALL inputs fp32, output fp32 (confirmed round 4).
  const float* x = (const float*)d_in[0];
  const float* Wqkv = (const float*)d_in[1];
  const float* bqkv = (const float*)d_in[2];
  const float* Wproj = (const float*)d_in[3];
  const float* bproj = (const float*)d_in[4];
  const float* Er = (const float*)d_in[5];
  float* out = (float*)d_out;

  if (ws_size < 4u * 8388608u) return;  // 32 MiB used, confirmed present

  uint8_t* w = (uint8_t*)d_ws;
  __bf16* Q = (__bf16*)w;  w += (size_t)BB * NHH * LL * HSS * 2;
  __bf16* Kt = (__bf16*)w; w += (size_t)BB * NHH * LL * HSS * 2;
  __bf16* Vt = (__bf16*)w; w += (size_t)BB * NHH * LL * HSS * 2;
  __bf16* Y = (__bf16*)w;  w += (size_t)BB * LL * DD * 2;

  // d_out scratch overlay (16.78 MB):
  //   Pre-GEMM1: WqkvT 6.29 MB @0, xb 8.39 MB @6.29M (both dead after GEMM1).
  //   During flash: Po1 8.39 MB @0, Lp0 0.26 MB @8.39M, Lp1 0.26 MB @8.65M,
  //   Erb 0.26 MB @14.68M (live through flash; no overlap).
  //   gemm_proj overwrites all of d_out last.
  __bf16* WqkvT = (__bf16*)d_out;
  __bf16* xb = (__bf16*)((uint8_t*)d_out + (size_t)3072 * 1024 * 2);
  __bf16* Erb = (__bf16*)((uint8_t*)d_out + (size_t)3072 * 1024 * 2 + (size_t)4096 * 1024 * 2);
  __bf16* Po1 = (__bf16*)d_out;
  float* Lp0 = (float*)((uint8_t*)d_out + (size_t)BB * LL * DD * 2);
  float* Lp1 = (float*)((uint8_t*)d_out + (size_t)BB * LL * DD * 2 + (size_t)BB * NHH * LL * 4);
  __bf16* Po0 = Y;       // combine reads+rewrites Y in place (same-thread RAW)
  __bf16* WprojT = Q;    // written after flash (Q dead by then)

  prep_k<<<dim3(3072, 1, 3), dim3(32, 8), 0, stream>>>(Wqkv, x, Er, WqkvT, xb, Erb);
  gemm_qkv_k<<<dim3(3072 / 128, 4096 / 128), 256, 0, stream>>>(
      xb, WqkvT, bqkv, Q, Kt, Vt);
  flash_k<<<dim3(BB * NHH, 32, 2), 256, 0, stream>>>(
      Q, Kt, Vt, Erb, Po0, Po1, Lp0, Lp1);
  combine_k<<<dim3(2048), 256, 0, stream>>>(Po0, Po1, Lp0, Lp1, Y);
  tconv_k<<<dim3(1024 / 32, 1024 / 32), dim3(32, 8), 0, stream>>>(Wproj, WprojT, 1024, 1024);
  gemm_proj_k<<<dim3(1024 / 64, 4096 / 128), 256, 0, stream>>>(Y, WprojT, bproj, out);
}